// Round 10
// baseline (1013.441 us; speedup 1.0000x reference)
//
#include <hip/hip_runtime.h>
#include <hip/hip_bf16.h>

#define NN 50000
#define EE 800000
#define DD 512
#define BB 64
#define LL 4
#define OUTC 2
#define EPSV 1e-5f

#define MT 128
#define NT 128
#define BK 64
#define HV8 (NN * DD / 8)    // 3,200,000 vectorized H-cast items

typedef _Float16 halfx8 __attribute__((ext_vector_type(8)));
typedef float floatx4 __attribute__((ext_vector_type(4)));

__device__ __forceinline__ floatx4 mfma16h(halfx8 a, halfx8 b, floatx4 c) {
    return __builtin_amdgcn_mfma_f32_16x16x32_f16(a, b, c, 0, 0, 0);
}

// async global->LDS, 16B per lane. LDS dest = wave-uniform base + lane*16.
__device__ __forceinline__ void ldg2lds16(const _Float16* g, _Float16* l) {
    __builtin_amdgcn_global_load_lds(
        (const __attribute__((address_space(1))) unsigned int*)g,
        (__attribute__((address_space(3))) unsigned int*)l, 16, 0, 0);
}

// ---------------- fused prep: x->fp16 (8-wide) + W transpose + edge atomics ----
__global__ void k_prep(const float* __restrict__ x, const float* __restrict__ Wc,
                       const int* __restrict__ ei, const int* __restrict__ sd,
                       _Float16* __restrict__ H, _Float16* __restrict__ WT,
                       float* __restrict__ deg, int* __restrict__ cnt) {
    int i = blockIdx.x * blockDim.x + threadIdx.x;
    if (i < HV8) {
        const float4* xp = (const float4*)x + (size_t)i * 2;
        float4 v0 = xp[0], v1 = xp[1];
        halfx8 h;
        h[0] = (_Float16)v0.x; h[1] = (_Float16)v0.y;
        h[2] = (_Float16)v0.z; h[3] = (_Float16)v0.w;
        h[4] = (_Float16)v1.x; h[5] = (_Float16)v1.y;
        h[6] = (_Float16)v1.z; h[7] = (_Float16)v1.w;
        ((halfx8*)H)[i] = h;
    }
    if (i < LL * DD * DD) {
        // i = (l<<18)+(k<<9)+n, n fastest -> coalesced read Wc[i]
        int l = i >> 18;
        int rem = i & ((DD * DD) - 1);
        int k = rem >> 9;
        int n = rem & (DD - 1);
        WT[(l << 18) + (n << 9) + k] = (_Float16)Wc[i];
    }
    if (i < EE) {
        int c = ei[EE + i];
        float w = (sd[i] == 1) ? 1.0f : 0.7f;
        atomicAdd(&deg[c], w);
        atomicAdd(&cnt[c], 1);
    }
}

// ---------------- scan block 1 (+ fused dis + fused graph bounds) ----------------
__global__ void k_scan1(const int* __restrict__ cnt, int* __restrict__ rowptr,
                        int* __restrict__ bsum, const float* __restrict__ deg,
                        float* __restrict__ dis, const int* __restrict__ batch,
                        int* __restrict__ gstart, int* __restrict__ gend) {
    __shared__ int sh[256];
    const int t = threadIdx.x;
    const int i = blockIdx.x * 256 + t;
    if (i < NN) {
        dis[i] = rsqrtf(fmaxf(deg[i] + 1.0f, EPSV));   // +1 = self-loop weight
        int g = batch[i];
        int gp = (i == 0) ? -1 : batch[i - 1];
        if (g != gp) gstart[g] = i;
        int gn = (i == NN - 1) ? BB : batch[i + 1];
        if (g != gn) gend[g] = i + 1;
    }
    int v = (i < NN) ? cnt[i] : 0;
    sh[t] = v;
    __syncthreads();
    for (int off = 1; off < 256; off <<= 1) {
        int y = (t >= off) ? sh[t - off] : 0;
        __syncthreads();
        if (t >= off) sh[t] += y;
        __syncthreads();
    }
    if (i < NN) rowptr[i] = sh[t] - v;   // exclusive
    if (t == 255) bsum[blockIdx.x] = sh[255];
}

// parallel single-block scan over the 196 block sums
__global__ void k_scan2(int* __restrict__ bsum, int* __restrict__ rowptr, int nb) {
    __shared__ int sh[256];
    const int t = threadIdx.x;
    int v = (t < nb) ? bsum[t] : 0;
    sh[t] = v;
    __syncthreads();
    for (int off = 1; off < 256; off <<= 1) {
        int y = (t >= off) ? sh[t - off] : 0;
        __syncthreads();
        if (t >= off) sh[t] += y;
        __syncthreads();
    }
    if (t < nb) bsum[t] = sh[t] - v;    // exclusive
    if (t == 255) rowptr[NN] = sh[255]; // total
}

__global__ void k_scan3(int* __restrict__ rowptr, const int* __restrict__ bsum) {
    int i = blockIdx.x * blockDim.x + threadIdx.x;
    if (i < NN) rowptr[i] += bsum[i >> 8];
}

// ---------------- CSR fill: per-dest src list + edge norm ----------------
__global__ void k_fill(const int* __restrict__ ei, const int* __restrict__ sd,
                       const float* __restrict__ dis, const int* __restrict__ rowptr,
                       int* __restrict__ fill, int* __restrict__ srcs,
                       float* __restrict__ enorm) {
    int e = blockIdx.x * blockDim.x + threadIdx.x;
    if (e >= EE) return;
    int s = ei[e];
    int c = ei[EE + e];
    float w = (sd[e] == 1) ? 1.0f : 0.7f;
    int p = rowptr[c] + atomicAdd(&fill[c], 1);
    srcs[p] = s;
    enorm[p] = dis[s] * w * dis[c];
}

// ---------------- GEMM: C[N,D] = H @ WT^T, fp16 MFMA, LDS staging, BK=64 ------
// BK=64 halves barrier count vs BK=32 (8 K-iters instead of 16); LDS 32 KB
// keeps ~3 blocks/CU (VGPR-limited). Staging: 4 rounds of 16B/thread per tile.
__launch_bounds__(256)
__global__ void k_gemm(const _Float16* __restrict__ A,
                       const _Float16* __restrict__ B,   // [n][k] transposed
                       _Float16* __restrict__ C) {
    __shared__ _Float16 sA[MT * BK];
    __shared__ _Float16 sB[NT * BK];

    const int t = threadIdx.x;
    const int wid = t >> 6;
    const int lane = t & 63;
    const int l15 = lane & 15;
    const int quad = lane >> 4;
    const int m0 = blockIdx.y * MT;
    const int n0 = blockIdx.x * NT;
    const int wr = (wid >> 1) * 64;   // wave row offset in tile
    const int wc = (wid & 1) * 64;    // wave col offset in tile

    // staging: round r (of 4) covers rows r*32..r*32+31 of a [128 x 64] fp16 tile.
    // thread t -> row r*32 + t/8, k-offset (t%8)*8. LDS dst = base + r*2048 + t*8.
    const int srow = t >> 3;
    const int skoff = (t & 7) * 8;
    const _Float16* gA = A + (size_t)(m0 + srow) * DD + skoff;
    const _Float16* gB = B + (size_t)(n0 + srow) * DD + skoff;
    _Float16* lA = sA + t * 8;   // first-lane value is wave base
    _Float16* lB = sB + t * 8;

    floatx4 acc[4][4];
#pragma unroll
    for (int i = 0; i < 4; i++)
#pragma unroll
        for (int j = 0; j < 4; j++) acc[i][j] = (floatx4){0.f, 0.f, 0.f, 0.f};

    for (int k0 = 0; k0 < DD; k0 += BK) {
        __syncthreads();   // previous compute done before overwriting LDS
#pragma unroll
        for (int r = 0; r < 4; r++) {
            ldg2lds16(gA + (size_t)r * 32 * DD + k0, lA + r * 2048);
            ldg2lds16(gB + (size_t)r * 32 * DD + k0, lB + r * 2048);
        }
        __syncthreads();   // compiler drains vmcnt before barrier

#pragma unroll
        for (int kk = 0; kk < BK; kk += 32) {
            halfx8 a[4], b[4];
#pragma unroll
            for (int i = 0; i < 4; i++) {
                a[i] = *(const halfx8*)&sA[(wr + i * 16 + l15) * BK + kk + quad * 8];
                b[i] = *(const halfx8*)&sB[(wc + i * 16 + l15) * BK + kk + quad * 8];
            }
#pragma unroll
            for (int i = 0; i < 4; i++)
#pragma unroll
                for (int j = 0; j < 4; j++)
                    acc[i][j] = mfma16h(a[i], b[j], acc[i][j]);
        }
    }

#pragma unroll
    for (int i = 0; i < 4; i++) {
        const int rbase = m0 + wr + i * 16 + quad * 4;
#pragma unroll
        for (int j = 0; j < 4; j++) {
            const int gcol = n0 + wc + j * 16 + l15;
#pragma unroll
            for (int r = 0; r < 4; r++) {
                const int grow = rbase + r;
                if (grow < NN) C[(size_t)grow * DD + gcol] = (_Float16)acc[i][j][r];
            }
        }
    }
}

// ---------------- aggregate + bias + BN + ReLU -> fp16 H ----------------
// 4 nodes per 256-thread block (1 wave per node, no barriers). Structurally
// floored at ~118us: FETCH ~400MB = cross-XCD L3 duplication (random edges);
// verified invariant across occupancy 46%..77% (R6/R7).
__launch_bounds__(256)
__global__ void k_agg(const _Float16* __restrict__ hw, const int* __restrict__ rowptr,
                      const int* __restrict__ srcs, const float* __restrict__ enorm,
                      const float* __restrict__ dis,
                      const float* __restrict__ bcl, const float* __restrict__ gl,
                      const float* __restrict__ bl_, const float* __restrict__ rml,
                      const float* __restrict__ rvl,
                      _Float16* __restrict__ H) {
    const int n = blockIdx.x * 4 + (threadIdx.x >> 6);
    const int lane = threadIdx.x & 63;
    if (n >= NN) return;
    const float dn = dis[n];
    const float sw = dn * dn;  // self-loop norm
    halfx8 a = ((const halfx8*)(hw + (size_t)n * DD))[lane];
    float acc[8];
#pragma unroll
    for (int k = 0; k < 8; k++) acc[k] = (float)a[k] * sw;
    const int s0 = rowptr[n], s1 = rowptr[n + 1];
    int i = s0;
    for (; i + 8 <= s1; i += 8) {
        int sv[8];
        float wv[8];
        halfx8 pv[8];
#pragma unroll
        for (int u = 0; u < 8; u++) { sv[u] = srcs[i + u]; wv[u] = enorm[i + u]; }
#pragma unroll
        for (int u = 0; u < 8; u++)
            pv[u] = ((const halfx8*)(hw + (size_t)sv[u] * DD))[lane];
#pragma unroll
        for (int u = 0; u < 8; u++)
#pragma unroll
            for (int k = 0; k < 8; k++) acc[k] = fmaf((float)pv[u][k], wv[u], acc[k]);
    }
    for (; i + 4 <= s1; i += 4) {
        int sv[4];
        float wv[4];
        halfx8 pv[4];
#pragma unroll
        for (int u = 0; u < 4; u++) { sv[u] = srcs[i + u]; wv[u] = enorm[i + u]; }
#pragma unroll
        for (int u = 0; u < 4; u++)
            pv[u] = ((const halfx8*)(hw + (size_t)sv[u] * DD))[lane];
#pragma unroll
        for (int u = 0; u < 4; u++)
#pragma unroll
            for (int k = 0; k < 8; k++) acc[k] = fmaf((float)pv[u][k], wv[u], acc[k]);
    }
    for (; i < s1; i++) {
        const int s = srcs[i];
        const float wn = enorm[i];
        halfx8 pb = ((const halfx8*)(hw + (size_t)s * DD))[lane];
#pragma unroll
        for (int k = 0; k < 8; k++) acc[k] = fmaf((float)pb[k], wn, acc[k]);
    }
    // BN + ReLU epilogue, channels lane*8 .. lane*8+7
    const float4* bc4 = (const float4*)bcl;
    const float4* g4 = (const float4*)gl;
    const float4* b4 = (const float4*)bl_;
    const float4* rm4 = (const float4*)rml;
    const float4* rv4 = (const float4*)rvl;
    halfx8 hv;
#pragma unroll
    for (int half4 = 0; half4 < 2; half4++) {
        const int cidx = lane * 2 + half4;
        float4 bcv = bc4[cidx], gv = g4[cidx], bv = b4[cidx], rmv = rm4[cidx], rvv = rv4[cidx];
        float h0 = fmaxf(gv.x * (acc[half4 * 4 + 0] + bcv.x - rmv.x) * rsqrtf(rvv.x + EPSV) + bv.x, 0.f);
        float h1 = fmaxf(gv.y * (acc[half4 * 4 + 1] + bcv.y - rmv.y) * rsqrtf(rvv.y + EPSV) + bv.y, 0.f);
        float h2 = fmaxf(gv.z * (acc[half4 * 4 + 2] + bcv.z - rmv.z) * rsqrtf(rvv.z + EPSV) + bv.z, 0.f);
        float h3 = fmaxf(gv.w * (acc[half4 * 4 + 3] + bcv.w - rmv.w) * rsqrtf(rvv.w + EPSV) + bv.w, 0.f);
        hv[half4 * 4 + 0] = (_Float16)h0;
        hv[half4 * 4 + 1] = (_Float16)h1;
        hv[half4 * 4 + 2] = (_Float16)h2;
        hv[half4 * 4 + 3] = (_Float16)h3;
    }
    ((halfx8*)(H + (size_t)n * DD))[lane] = hv;
}

// ---------------- mean/max pooling (8 slices per graph) ----------------
__launch_bounds__(512)
__global__ void k_pool(const _Float16* __restrict__ H,
                       const int* __restrict__ gstart, const int* __restrict__ gend,
                       float* __restrict__ psum, unsigned int* __restrict__ pmax) {
    const int g = blockIdx.x;
    const int sl = blockIdx.y;
    const int c = threadIdx.x;
    const int s0 = gstart[g], e0 = gend[g];
    if (e0 <= s0) return;
    const int len = e0 - s0;
    const int chunk = (len + 7) >> 3;
    const int lo = s0 + sl * chunk;
    const int hi = min(lo + chunk, e0);
    float sum = 0.f, mx = 0.f;
    for (int n = lo; n < hi; n++) {
        float v = (float)H[(size_t)n * DD + c];
        sum += v;
        mx = fmaxf(mx, v);
    }
    if (lo < hi) {
        atomicAdd(&psum[g * DD + c], sum);
        atomicMax(&pmax[g * DD + c], __float_as_uint(fmaxf(mx, 0.f)));  // h >= 0
    }
}

// ---------------- final linear + log_softmax: one wave per graph ----------------
__launch_bounds__(64)
__global__ void k_final(const float* __restrict__ psum, const unsigned int* __restrict__ pmax,
                        const int* __restrict__ gstart, const int* __restrict__ gend,
                        const float* __restrict__ Wlin, const float* __restrict__ blin,
                        float* __restrict__ out) {
    const int g = blockIdx.x;
    const int lane = threadIdx.x;
    int cntg = gend[g] - gstart[g];
    if (cntg < 1) cntg = 1;   // empty graph: psum/pmax are 0, inv irrelevant
    const float inv = 1.0f / (float)cntg;
    float z0 = 0.f, z1 = 0.f;
#pragma unroll
    for (int j = 0; j < 8; j++) {
        const int k = j * 64 + lane;
        float mean = psum[g * DD + k] * inv;
        float mx = __uint_as_float(pmax[g * DD + k]);
        z0 += mean * Wlin[k * OUTC + 0] + mx * Wlin[(DD + k) * OUTC + 0];
        z1 += mean * Wlin[k * OUTC + 1] + mx * Wlin[(DD + k) * OUTC + 1];
    }
#pragma unroll
    for (int off = 32; off > 0; off >>= 1) {
        z0 += __shfl_down(z0, off);
        z1 += __shfl_down(z1, off);
    }
    if (lane == 0) {
        z0 += blin[0];
        z1 += blin[1];
        float m = fmaxf(z0, z1);
        float ls = m + logf(expf(z0 - m) + expf(z1 - m));
        out[g * OUTC + 0] = z0 - ls;
        out[g * OUTC + 1] = z1 - ls;
    }
}

extern "C" void kernel_launch(void* const* d_in, const int* in_sizes, int n_in,
                              void* d_out, int out_size, void* d_ws, size_t ws_size,
                              hipStream_t stream) {
    const float* x = (const float*)d_in[0];
    const int* ei = (const int*)d_in[1];
    const int* batch = (const int*)d_in[2];
    const int* sd = (const int*)d_in[3];
    const float* Wc = (const float*)d_in[4];
    const float* bc = (const float*)d_in[5];
    const float* gamma = (const float*)d_in[6];
    const float* beta = (const float*)d_in[7];
    const float* rmean = (const float*)d_in[8];
    const float* rvar = (const float*)d_in[9];
    const float* Wlin = (const float*)d_in[10];
    const float* blin = (const float*)d_in[11];
    float* out = (float*)d_out;

    char* p = (char*)d_ws;
    auto alloc = [&](size_t bytes) {
        char* r = p;
        p += (bytes + 255) & ~(size_t)255;
        return r;
    };
    _Float16* hw = (_Float16*)alloc((size_t)NN * DD * 2);
    _Float16* H = (_Float16*)alloc((size_t)NN * DD * 2);
    _Float16* WT = (_Float16*)alloc((size_t)LL * DD * DD * 2);
    // --- zero-initialized region starts here (hipMemsetAsync) ---
    char* zbase = p;
    float* deg = (float*)alloc(NN * 4);
    float* dis = (float*)alloc(NN * 4);
    int* cnt = (int*)alloc(NN * 4);
    int* fill = (int*)alloc(NN * 4);
    int* rowptr = (int*)alloc((NN + 1) * 4);
    int* bsum = (int*)alloc(256 * 4);
    int* srcs = (int*)alloc(EE * 4);
    float* enorm = (float*)alloc(EE * 4);
    int* gstart = (int*)alloc(BB * 4);
    int* gend = (int*)alloc(BB * 4);
    float* psum = (float*)alloc(BB * DD * 4);
    unsigned int* pmax = (unsigned int*)alloc(BB * DD * 4);
    size_t zbytes = (size_t)(p - zbase);
    (void)ws_size; (void)in_sizes; (void)n_in; (void)out_size;

    const int nb256 = (NN + 255) / 256;          // 196
    const int eb256 = (EE + 255) / 256;          // 3125

    hipMemsetAsync(zbase, 0, zbytes, stream);
    k_prep<<<(HV8 + 255) / 256, 256, 0, stream>>>(x, Wc, ei, sd, H, WT, deg, cnt);
    k_scan1<<<nb256, 256, 0, stream>>>(cnt, rowptr, bsum, deg, dis, batch, gstart, gend);
    k_scan2<<<1, 256, 0, stream>>>(bsum, rowptr, nb256);
    k_scan3<<<nb256, 256, 0, stream>>>(rowptr, bsum);
    k_fill<<<eb256, 256, 0, stream>>>(ei, sd, dis, rowptr, fill, srcs, enorm);

    // n-tile fastest so co-resident blocks share A slabs in L2/L3
    dim3 ggrid(DD / NT, (NN + MT - 1) / MT);  // (4, 391)
    for (int l = 0; l < LL; l++) {
        k_gemm<<<ggrid, 256, 0, stream>>>(H, WT + (size_t)l * DD * DD, hw);
        k_agg<<<(NN + 3) / 4, 256, 0, stream>>>(hw, rowptr, srcs, enorm, dis,
                                                bc + l * DD, gamma + l * DD, beta + l * DD,
                                                rmean + l * DD, rvar + l * DD, H);
    }

    k_pool<<<dim3(BB, 8), 512, 0, stream>>>(H, gstart, gend, psum, pmax);
    k_final<<<BB, 64, 0, stream>>>(psum, pmax, gstart, gend, Wlin, blin, out);
}

// Round 11
// 992.579 us; speedup vs baseline: 1.0210x; 1.0210x over previous
//
#include <hip/hip_runtime.h>
#include <hip/hip_bf16.h>

#define NN 50000
#define EE 800000
#define DD 512
#define BB 64
#define LL 4
#define OUTC 2
#define EPSV 1e-5f

#define MTG 64               // gemm M-tile (A read exactly once over the grid)
#define NTG 512              // gemm N-tile = full D
#define BKG 32
#define HV8 (NN * DD / 8)    // 3,200,000 vectorized H-cast items

typedef _Float16 halfx8 __attribute__((ext_vector_type(8)));
typedef float floatx4 __attribute__((ext_vector_type(4)));

__device__ __forceinline__ floatx4 mfma16h(halfx8 a, halfx8 b, floatx4 c) {
    return __builtin_amdgcn_mfma_f32_16x16x32_f16(a, b, c, 0, 0, 0);
}

// async global->LDS, 16B per lane. LDS dest = wave-uniform base + lane*16.
__device__ __forceinline__ void ldg2lds16(const _Float16* g, _Float16* l) {
    __builtin_amdgcn_global_load_lds(
        (const __attribute__((address_space(1))) unsigned int*)g,
        (__attribute__((address_space(3))) unsigned int*)l, 16, 0, 0);
}

// ---------------- fused prep: x->fp16 (8-wide) + W transpose + edge atomics ----
__global__ void k_prep(const float* __restrict__ x, const float* __restrict__ Wc,
                       const int* __restrict__ ei, const int* __restrict__ sd,
                       _Float16* __restrict__ H, _Float16* __restrict__ WT,
                       float* __restrict__ deg, int* __restrict__ cnt) {
    int i = blockIdx.x * blockDim.x + threadIdx.x;
    if (i < HV8) {
        const float4* xp = (const float4*)x + (size_t)i * 2;
        float4 v0 = xp[0], v1 = xp[1];
        halfx8 h;
        h[0] = (_Float16)v0.x; h[1] = (_Float16)v0.y;
        h[2] = (_Float16)v0.z; h[3] = (_Float16)v0.w;
        h[4] = (_Float16)v1.x; h[5] = (_Float16)v1.y;
        h[6] = (_Float16)v1.z; h[7] = (_Float16)v1.w;
        ((halfx8*)H)[i] = h;
    }
    if (i < LL * DD * DD) {
        // i = (l<<18)+(k<<9)+n, n fastest -> coalesced read Wc[i]
        int l = i >> 18;
        int rem = i & ((DD * DD) - 1);
        int k = rem >> 9;
        int n = rem & (DD - 1);
        WT[(l << 18) + (n << 9) + k] = (_Float16)Wc[i];
    }
    if (i < EE) {
        int c = ei[EE + i];
        float w = (sd[i] == 1) ? 1.0f : 0.7f;
        atomicAdd(&deg[c], w);
        atomicAdd(&cnt[c], 1);
    }
}

// ---------------- scan block 1 (+ fused dis + fused graph bounds) ----------------
__global__ void k_scan1(const int* __restrict__ cnt, int* __restrict__ rowptr,
                        int* __restrict__ bsum, const float* __restrict__ deg,
                        float* __restrict__ dis, const int* __restrict__ batch,
                        int* __restrict__ gstart, int* __restrict__ gend) {
    __shared__ int sh[256];
    const int t = threadIdx.x;
    const int i = blockIdx.x * 256 + t;
    if (i < NN) {
        dis[i] = rsqrtf(fmaxf(deg[i] + 1.0f, EPSV));   // +1 = self-loop weight
        int g = batch[i];
        int gp = (i == 0) ? -1 : batch[i - 1];
        if (g != gp) gstart[g] = i;
        int gn = (i == NN - 1) ? BB : batch[i + 1];
        if (g != gn) gend[g] = i + 1;
    }
    int v = (i < NN) ? cnt[i] : 0;
    sh[t] = v;
    __syncthreads();
    for (int off = 1; off < 256; off <<= 1) {
        int y = (t >= off) ? sh[t - off] : 0;
        __syncthreads();
        if (t >= off) sh[t] += y;
        __syncthreads();
    }
    if (i < NN) rowptr[i] = sh[t] - v;   // exclusive
    if (t == 255) bsum[blockIdx.x] = sh[255];
}

// parallel single-block scan over the 196 block sums
__global__ void k_scan2(int* __restrict__ bsum, int* __restrict__ rowptr, int nb) {
    __shared__ int sh[256];
    const int t = threadIdx.x;
    int v = (t < nb) ? bsum[t] : 0;
    sh[t] = v;
    __syncthreads();
    for (int off = 1; off < 256; off <<= 1) {
        int y = (t >= off) ? sh[t - off] : 0;
        __syncthreads();
        if (t >= off) sh[t] += y;
        __syncthreads();
    }
    if (t < nb) bsum[t] = sh[t] - v;    // exclusive
    if (t == 255) rowptr[NN] = sh[255]; // total
}

__global__ void k_scan3(int* __restrict__ rowptr, const int* __restrict__ bsum) {
    int i = blockIdx.x * blockDim.x + threadIdx.x;
    if (i < NN) rowptr[i] += bsum[i >> 8];
}

// ---------------- CSR fill: per-dest src list + edge norm ----------------
__global__ void k_fill(const int* __restrict__ ei, const int* __restrict__ sd,
                       const float* __restrict__ dis, const int* __restrict__ rowptr,
                       int* __restrict__ fill, int* __restrict__ srcs,
                       float* __restrict__ enorm) {
    int e = blockIdx.x * blockDim.x + threadIdx.x;
    if (e >= EE) return;
    int s = ei[e];
    int c = ei[EE + e];
    float w = (sd[e] == 1) ? 1.0f : 0.7f;
    int p = rowptr[c] + atomicAdd(&fill[c], 1);
    srcs[p] = s;
    enorm[p] = dis[s] * w * dis[c];
}

// ---------------- GEMM: C[N,D] = H @ WT^T, MT=64 x NT=512 (full D) ------
// Thin-shape-aware tiling: one block column -> A (50 MB) fetched exactly once;
// B (512 KB) re-read per block but L2-resident. 8 waves, one 64x64 tile each.
__launch_bounds__(512)
__global__ void k_gemm(const _Float16* __restrict__ A,
                       const _Float16* __restrict__ B,   // [n][k] transposed
                       _Float16* __restrict__ C) {
    __shared__ _Float16 sA[MTG * BKG];   // 4 KB
    __shared__ _Float16 sB[NTG * BKG];   // 32 KB

    const int t = threadIdx.x;
    const int wid = t >> 6;          // 0..7
    const int lane = t & 63;
    const int l15 = lane & 15;
    const int quad = lane >> 4;
    const int m0 = blockIdx.x * MTG;
    const int wc = wid * 64;         // wave col base (8 x 64 = 512)

    // A staging (waves 0..3 only): row t>>2 (64 rows x 4 thr), koff (t&3)*8
    int arow = m0 + (t >> 2);
    if (arow > NN - 1) arow = NN - 1;   // clamp loads; stores guarded
    const _Float16* gA = A + (size_t)arow * DD + (t & 3) * 8;
    _Float16* lA = sA + t * 8;
    // B staging (all 8 waves): round r covers rows r*128 .. r*128+127
    const _Float16* gB = B + (size_t)(t >> 2) * DD + (t & 3) * 8;
    _Float16* lB = sB + t * 8;

    floatx4 acc[4][4];
#pragma unroll
    for (int i = 0; i < 4; i++)
#pragma unroll
        for (int j = 0; j < 4; j++) acc[i][j] = (floatx4){0.f, 0.f, 0.f, 0.f};

    for (int k0 = 0; k0 < DD; k0 += BKG) {
        __syncthreads();   // previous compute done before overwriting LDS
        if (t < 256) ldg2lds16(gA + k0, lA);          // wave-uniform branch
#pragma unroll
        for (int r = 0; r < 4; r++)
            ldg2lds16(gB + (size_t)r * 128 * DD + k0, lB + r * 4096);
        __syncthreads();   // compiler drains vmcnt before barrier

        halfx8 a[4], b[4];
#pragma unroll
        for (int i = 0; i < 4; i++)
            a[i] = *(const halfx8*)&sA[(i * 16 + l15) * BKG + quad * 8];
#pragma unroll
        for (int j = 0; j < 4; j++)
            b[j] = *(const halfx8*)&sB[(wc + j * 16 + l15) * BKG + quad * 8];
#pragma unroll
        for (int i = 0; i < 4; i++)
#pragma unroll
            for (int j = 0; j < 4; j++)
                acc[i][j] = mfma16h(a[i], b[j], acc[i][j]);
    }

#pragma unroll
    for (int i = 0; i < 4; i++) {
        const int rbase = m0 + i * 16 + quad * 4;
#pragma unroll
        for (int j = 0; j < 4; j++) {
            const int gcol = wc + j * 16 + l15;
#pragma unroll
            for (int r = 0; r < 4; r++) {
                const int grow = rbase + r;
                if (grow < NN) C[(size_t)grow * DD + gcol] = (_Float16)acc[i][j][r];
            }
        }
    }
}

// ---------------- aggregate + bias + BN + ReLU -> fp16 H ----------------
// 4 nodes per 256-thread block (1 wave per node, no barriers). Structurally
// floored at ~118us: FETCH ~400MB = cross-XCD L3 duplication (random edges);
// verified invariant across occupancy 46%..77% (R6/R7).
__launch_bounds__(256)
__global__ void k_agg(const _Float16* __restrict__ hw, const int* __restrict__ rowptr,
                      const int* __restrict__ srcs, const float* __restrict__ enorm,
                      const float* __restrict__ dis,
                      const float* __restrict__ bcl, const float* __restrict__ gl,
                      const float* __restrict__ bl_, const float* __restrict__ rml,
                      const float* __restrict__ rvl,
                      _Float16* __restrict__ H) {
    const int n = blockIdx.x * 4 + (threadIdx.x >> 6);
    const int lane = threadIdx.x & 63;
    if (n >= NN) return;
    const float dn = dis[n];
    const float sw = dn * dn;  // self-loop norm
    halfx8 a = ((const halfx8*)(hw + (size_t)n * DD))[lane];
    float acc[8];
#pragma unroll
    for (int k = 0; k < 8; k++) acc[k] = (float)a[k] * sw;
    const int s0 = rowptr[n], s1 = rowptr[n + 1];
    int i = s0;
    for (; i + 8 <= s1; i += 8) {
        int sv[8];
        float wv[8];
        halfx8 pv[8];
#pragma unroll
        for (int u = 0; u < 8; u++) { sv[u] = srcs[i + u]; wv[u] = enorm[i + u]; }
#pragma unroll
        for (int u = 0; u < 8; u++)
            pv[u] = ((const halfx8*)(hw + (size_t)sv[u] * DD))[lane];
#pragma unroll
        for (int u = 0; u < 8; u++)
#pragma unroll
            for (int k = 0; k < 8; k++) acc[k] = fmaf((float)pv[u][k], wv[u], acc[k]);
    }
    for (; i + 4 <= s1; i += 4) {
        int sv[4];
        float wv[4];
        halfx8 pv[4];
#pragma unroll
        for (int u = 0; u < 4; u++) { sv[u] = srcs[i + u]; wv[u] = enorm[i + u]; }
#pragma unroll
        for (int u = 0; u < 4; u++)
            pv[u] = ((const halfx8*)(hw + (size_t)sv[u] * DD))[lane];
#pragma unroll
        for (int u = 0; u < 4; u++)
#pragma unroll
            for (int k = 0; k < 8; k++) acc[k] = fmaf((float)pv[u][k], wv[u], acc[k]);
    }
    for (; i < s1; i++) {
        const int s = srcs[i];
        const float wn = enorm[i];
        halfx8 pb = ((const halfx8*)(hw + (size_t)s * DD))[lane];
#pragma unroll
        for (int k = 0; k < 8; k++) acc[k] = fmaf((float)pb[k], wn, acc[k]);
    }
    // BN + ReLU epilogue, channels lane*8 .. lane*8+7
    const float4* bc4 = (const float4*)bcl;
    const float4* g4 = (const float4*)gl;
    const float4* b4 = (const float4*)bl_;
    const float4* rm4 = (const float4*)rml;
    const float4* rv4 = (const float4*)rvl;
    halfx8 hv;
#pragma unroll
    for (int half4 = 0; half4 < 2; half4++) {
        const int cidx = lane * 2 + half4;
        float4 bcv = bc4[cidx], gv = g4[cidx], bv = b4[cidx], rmv = rm4[cidx], rvv = rv4[cidx];
        float h0 = fmaxf(gv.x * (acc[half4 * 4 + 0] + bcv.x - rmv.x) * rsqrtf(rvv.x + EPSV) + bv.x, 0.f);
        float h1 = fmaxf(gv.y * (acc[half4 * 4 + 1] + bcv.y - rmv.y) * rsqrtf(rvv.y + EPSV) + bv.y, 0.f);
        float h2 = fmaxf(gv.z * (acc[half4 * 4 + 2] + bcv.z - rmv.z) * rsqrtf(rvv.z + EPSV) + bv.z, 0.f);
        float h3 = fmaxf(gv.w * (acc[half4 * 4 + 3] + bcv.w - rmv.w) * rsqrtf(rvv.w + EPSV) + bv.w, 0.f);
        hv[half4 * 4 + 0] = (_Float16)h0;
        hv[half4 * 4 + 1] = (_Float16)h1;
        hv[half4 * 4 + 2] = (_Float16)h2;
        hv[half4 * 4 + 3] = (_Float16)h3;
    }
    ((halfx8*)(H + (size_t)n * DD))[lane] = hv;
}

// ---------------- mean/max pooling (8 slices per graph) ----------------
__launch_bounds__(512)
__global__ void k_pool(const _Float16* __restrict__ H,
                       const int* __restrict__ gstart, const int* __restrict__ gend,
                       float* __restrict__ psum, unsigned int* __restrict__ pmax) {
    const int g = blockIdx.x;
    const int sl = blockIdx.y;
    const int c = threadIdx.x;
    const int s0 = gstart[g], e0 = gend[g];
    if (e0 <= s0) return;
    const int len = e0 - s0;
    const int chunk = (len + 7) >> 3;
    const int lo = s0 + sl * chunk;
    const int hi = min(lo + chunk, e0);
    float sum = 0.f, mx = 0.f;
    for (int n = lo; n < hi; n++) {
        float v = (float)H[(size_t)n * DD + c];
        sum += v;
        mx = fmaxf(mx, v);
    }
    if (lo < hi) {
        atomicAdd(&psum[g * DD + c], sum);
        atomicMax(&pmax[g * DD + c], __float_as_uint(fmaxf(mx, 0.f)));  // h >= 0
    }
}

// ---------------- final linear + log_softmax: one wave per graph ----------------
__launch_bounds__(64)
__global__ void k_final(const float* __restrict__ psum, const unsigned int* __restrict__ pmax,
                        const int* __restrict__ gstart, const int* __restrict__ gend,
                        const float* __restrict__ Wlin, const float* __restrict__ blin,
                        float* __restrict__ out) {
    const int g = blockIdx.x;
    const int lane = threadIdx.x;
    int cntg = gend[g] - gstart[g];
    if (cntg < 1) cntg = 1;   // empty graph: psum/pmax are 0, inv irrelevant
    const float inv = 1.0f / (float)cntg;
    float z0 = 0.f, z1 = 0.f;
#pragma unroll
    for (int j = 0; j < 8; j++) {
        const int k = j * 64 + lane;
        float mean = psum[g * DD + k] * inv;
        float mx = __uint_as_float(pmax[g * DD + k]);
        z0 += mean * Wlin[k * OUTC + 0] + mx * Wlin[(DD + k) * OUTC + 0];
        z1 += mean * Wlin[k * OUTC + 1] + mx * Wlin[(DD + k) * OUTC + 1];
    }
#pragma unroll
    for (int off = 32; off > 0; off >>= 1) {
        z0 += __shfl_down(z0, off);
        z1 += __shfl_down(z1, off);
    }
    if (lane == 0) {
        z0 += blin[0];
        z1 += blin[1];
        float m = fmaxf(z0, z1);
        float ls = m + logf(expf(z0 - m) + expf(z1 - m));
        out[g * OUTC + 0] = z0 - ls;
        out[g * OUTC + 1] = z1 - ls;
    }
}

extern "C" void kernel_launch(void* const* d_in, const int* in_sizes, int n_in,
                              void* d_out, int out_size, void* d_ws, size_t ws_size,
                              hipStream_t stream) {
    const float* x = (const float*)d_in[0];
    const int* ei = (const int*)d_in[1];
    const int* batch = (const int*)d_in[2];
    const int* sd = (const int*)d_in[3];
    const float* Wc = (const float*)d_in[4];
    const float* bc = (const float*)d_in[5];
    const float* gamma = (const float*)d_in[6];
    const float* beta = (const float*)d_in[7];
    const float* rmean = (const float*)d_in[8];
    const float* rvar = (const float*)d_in[9];
    const float* Wlin = (const float*)d_in[10];
    const float* blin = (const float*)d_in[11];
    float* out = (float*)d_out;

    char* p = (char*)d_ws;
    auto alloc = [&](size_t bytes) {
        char* r = p;
        p += (bytes + 255) & ~(size_t)255;
        return r;
    };
    _Float16* hw = (_Float16*)alloc((size_t)NN * DD * 2);
    _Float16* H = (_Float16*)alloc((size_t)NN * DD * 2);
    _Float16* WT = (_Float16*)alloc((size_t)LL * DD * DD * 2);
    // --- zero-initialized region starts here (hipMemsetAsync) ---
    char* zbase = p;
    float* deg = (float*)alloc(NN * 4);
    float* dis = (float*)alloc(NN * 4);
    int* cnt = (int*)alloc(NN * 4);
    int* fill = (int*)alloc(NN * 4);
    int* rowptr = (int*)alloc((NN + 1) * 4);
    int* bsum = (int*)alloc(256 * 4);
    int* srcs = (int*)alloc(EE * 4);
    float* enorm = (float*)alloc(EE * 4);
    int* gstart = (int*)alloc(BB * 4);
    int* gend = (int*)alloc(BB * 4);
    float* psum = (float*)alloc(BB * DD * 4);
    unsigned int* pmax = (unsigned int*)alloc(BB * DD * 4);
    size_t zbytes = (size_t)(p - zbase);
    (void)ws_size; (void)in_sizes; (void)n_in; (void)out_size;

    const int nb256 = (NN + 255) / 256;          // 196
    const int eb256 = (EE + 255) / 256;          // 3125

    hipMemsetAsync(zbase, 0, zbytes, stream);
    k_prep<<<(HV8 + 255) / 256, 256, 0, stream>>>(x, Wc, ei, sd, H, WT, deg, cnt);
    k_scan1<<<nb256, 256, 0, stream>>>(cnt, rowptr, bsum, deg, dis, batch, gstart, gend);
    k_scan2<<<1, 256, 0, stream>>>(bsum, rowptr, nb256);
    k_scan3<<<nb256, 256, 0, stream>>>(rowptr, bsum);
    k_fill<<<eb256, 256, 0, stream>>>(ei, sd, dis, rowptr, fill, srcs, enorm);

    const int ggrid = (NN + MTG - 1) / MTG;   // 782 blocks, A read exactly once
    for (int l = 0; l < LL; l++) {
        k_gemm<<<ggrid, 512, 0, stream>>>(H, WT + (size_t)l * DD * DD, hw);
        k_agg<<<(NN + 3) / 4, 256, 0, stream>>>(hw, rowptr, srcs, enorm, dis,
                                                bc + l * DD, gamma + l * DD, beta + l * DD,
                                                rmean + l * DD, rvar + l * DD, H);
    }

    k_pool<<<dim3(BB, 8), 512, 0, stream>>>(H, gstart, gend, psum, pmax);
    k_final<<<BB, 64, 0, stream>>>(psum, pmax, gstart, gend, Wlin, blin, out);
}